// Round 2
// baseline (298.114 us; speedup 1.0000x reference)
//
#include <hip/hip_runtime.h>
#include <stdint.h>

// Problem constants (fixed by the reference file)
#define NPTS   4194304
#define IMG_H  1024
#define IMG_W  1280
#define NPIX   (IMG_H * IMG_W)
#define NBUF   8                      // one z-buffer per XCD (gfx950 has 8)

static const unsigned long long KEY_SENTINEL = ~0ULL;

// ---------------------------------------------------------------------------
// Init: fill n_u64 u64 words with sentinel (ws is poisoned to 0xAA each run).
// Vectorized as ulonglong2 (16B per thread).
// ---------------------------------------------------------------------------
__global__ void init_keys_vec(ulonglong2* __restrict__ keys, int n_vec2) {
    int i = blockIdx.x * blockDim.x + threadIdx.x;
    if (i < n_vec2) keys[i] = ulonglong2{~0ULL, ~0ULL};
}

// ---------------------------------------------------------------------------
// Scatter (per-XCD path): 4 points per thread via 3x float4 loads.
// Key = (z_bits << 32) | index; positive-float bits are order-preserving, so
// min(key) == lexicographic min(z, index) == the stable-argsort winner.
// Workgroup-scope atomics are performed in the local XCD's L2; each XCD owns
// a private buffer (indexed by HW_REG_XCC_ID) so no cross-XCD atomicity is
// required. A later dispatch merges the 8 buffers.
// ---------------------------------------------------------------------------
__device__ __forceinline__ void project_and_min(
    float x, float y, float z, unsigned int idx,
    float fx, float fy, float cx, float cy, int width, int height,
    unsigned long long* __restrict__ buf) {
    // Match numpy bit-for-bit: IEEE f32 mul, div, add, round-half-even.
    float uf = rintf(fx * x / z + cx);
    float vf = rintf(fy * y / z + cy);
    bool valid = (z > 0.0f) &&
                 (uf >= 0.0f) && (uf < (float)width) &&
                 (vf >= 0.0f) && (vf < (float)height);
    if (!valid) return;
    int pix = (int)vf * width + (int)uf;
    unsigned long long key =
        ((unsigned long long)__float_as_uint(z) << 32) | idx;
    __hip_atomic_fetch_min(&buf[pix], key,
                           __ATOMIC_RELAXED, __HIP_MEMORY_SCOPE_WORKGROUP);
}

__global__ void scatter_points_xcd(const float4* __restrict__ pts4,
                                   const float* __restrict__ Kmat,
                                   const int* __restrict__ heightp,
                                   const int* __restrict__ widthp,
                                   unsigned long long* __restrict__ keys,
                                   int n_quads) {
    int t = blockIdx.x * blockDim.x + threadIdx.x;
    if (t >= n_quads) return;

    unsigned int xcc;
    asm volatile("s_getreg_b32 %0, hwreg(HW_REG_XCC_ID)" : "=s"(xcc));
    unsigned long long* buf = keys + (size_t)(xcc & 7) * NPIX;

    float fx = Kmat[0], cx = Kmat[2];
    float fy = Kmat[4], cy = Kmat[5];
    int width = widthp[0], height = heightp[0];

    float4 a = pts4[3 * t + 0];
    float4 b = pts4[3 * t + 1];
    float4 c = pts4[3 * t + 2];
    unsigned int i0 = 4u * (unsigned int)t;

    project_and_min(a.x, a.y, a.z, i0 + 0, fx, fy, cx, cy, width, height, buf);
    project_and_min(a.w, b.x, b.y, i0 + 1, fx, fy, cx, cy, width, height, buf);
    project_and_min(b.z, b.w, c.x, i0 + 2, fx, fy, cx, cy, width, height, buf);
    project_and_min(c.y, c.z, c.w, i0 + 3, fx, fy, cx, cy, width, height, buf);
}

// Fallback scatter (single buffer, device-scope) if ws is too small.
__global__ void scatter_points_dev(const float4* __restrict__ pts4,
                                   const float* __restrict__ Kmat,
                                   const int* __restrict__ heightp,
                                   const int* __restrict__ widthp,
                                   unsigned long long* __restrict__ keys,
                                   int n_quads) {
    int t = blockIdx.x * blockDim.x + threadIdx.x;
    if (t >= n_quads) return;

    float fx = Kmat[0], cx = Kmat[2];
    float fy = Kmat[4], cy = Kmat[5];
    int width = widthp[0], height = heightp[0];

    float4 a = pts4[3 * t + 0];
    float4 b = pts4[3 * t + 1];
    float4 c = pts4[3 * t + 2];
    unsigned int i0 = 4u * (unsigned int)t;

    struct P { float x, y, z; };
    P p[4] = {{a.x, a.y, a.z}, {a.w, b.x, b.y}, {b.z, b.w, c.x}, {c.y, c.z, c.w}};
#pragma unroll
    for (int k = 0; k < 4; ++k) {
        float uf = rintf(fx * p[k].x / p[k].z + cx);
        float vf = rintf(fy * p[k].y / p[k].z + cy);
        bool valid = (p[k].z > 0.0f) &&
                     (uf >= 0.0f) && (uf < (float)width) &&
                     (vf >= 0.0f) && (vf < (float)height);
        if (!valid) continue;
        int pix = (int)vf * width + (int)uf;
        unsigned long long key =
            ((unsigned long long)__float_as_uint(p[k].z) << 32) | (i0 + k);
        atomicMin(&keys[pix], key);
    }
}

// ---------------------------------------------------------------------------
// Resolve: min-reduce the NBUF per-XCD buffers, gather winner color.
// ---------------------------------------------------------------------------
template <int NB>
__global__ void resolve_pixels_merge(const unsigned long long* __restrict__ keys,
                                     const float* __restrict__ colors,
                                     float* __restrict__ out,
                                     int npix) {
    int i = blockIdx.x * blockDim.x + threadIdx.x;
    if (i >= npix) return;

    unsigned long long best = keys[i];
#pragma unroll
    for (int b = 1; b < NB; ++b) {
        unsigned long long k = keys[(size_t)b * NPIX + i];
        best = (k < best) ? k : best;
    }

    float r = 0.0f, g = 0.0f, bl = 0.0f;
    if (best != KEY_SENTINEL) {
        unsigned int idx = (unsigned int)(best & 0xFFFFFFFFu);
        r  = colors[3 * idx + 0];
        g  = colors[3 * idx + 1];
        bl = colors[3 * idx + 2];
    }
    out[3 * i + 0] = r;
    out[3 * i + 1] = g;
    out[3 * i + 2] = bl;
}

// ---------------------------------------------------------------------------
extern "C" void kernel_launch(void* const* d_in, const int* in_sizes, int n_in,
                              void* d_out, int out_size, void* d_ws, size_t ws_size,
                              hipStream_t stream) {
    const float4* pts4  = (const float4*)d_in[0];  // (N,3) viewed as float4[3N/4]
    const float* colors = (const float*)d_in[1];   // (N,3)
    const float* Kmat   = (const float*)d_in[2];   // (3,3)
    const int*   hgt    = (const int*)d_in[3];     // scalar
    const int*   wid    = (const int*)d_in[4];     // scalar

    float* out = (float*)d_out;                    // (H,W,3) f32
    unsigned long long* keys = (unsigned long long*)d_ws;

    int n       = in_sizes[0] / 3;                 // number of points
    int n_quads = n / 4;                           // N divisible by 4
    const int B = 256;

    const size_t need = (size_t)NBUF * NPIX * sizeof(unsigned long long);
    if (ws_size >= need) {
        // Per-XCD path: 8 private buffers, workgroup-scope (L2-local) atomics.
        int n_vec2 = (NBUF * NPIX) / 2;
        init_keys_vec<<<(n_vec2 + B - 1) / B, B, 0, stream>>>(
            (ulonglong2*)keys, n_vec2);
        scatter_points_xcd<<<(n_quads + B - 1) / B, B, 0, stream>>>(
            pts4, Kmat, hgt, wid, keys, n_quads);
        resolve_pixels_merge<NBUF><<<(NPIX + B - 1) / B, B, 0, stream>>>(
            keys, colors, out, NPIX);
    } else {
        // Fallback: single buffer, device-scope atomics.
        int n_vec2 = NPIX / 2;
        init_keys_vec<<<(n_vec2 + B - 1) / B, B, 0, stream>>>(
            (ulonglong2*)keys, n_vec2);
        scatter_points_dev<<<(n_quads + B - 1) / B, B, 0, stream>>>(
            pts4, Kmat, hgt, wid, keys, n_quads);
        resolve_pixels_merge<1><<<(NPIX + B - 1) / B, B, 0, stream>>>(
            keys, colors, out, NPIX);
    }
}

// Round 3
// 260.122 us; speedup vs baseline: 1.1461x; 1.1461x over previous
//
#include <hip/hip_runtime.h>
#include <stdint.h>

// Problem constants (fixed by the reference file)
#define NPTS   4194304
#define IMG_H  1024
#define IMG_W  1280
#define NPIX   (IMG_H * IMG_W)

static const unsigned long long KEY_SENTINEL = ~0ULL;

// ---------------------------------------------------------------------------
// Init: fill the NPIX u64 keys with sentinel (ws is poisoned to 0xAA each run).
// ---------------------------------------------------------------------------
__global__ void init_keys_vec(ulonglong2* __restrict__ keys, int n_vec2) {
    int i = blockIdx.x * blockDim.x + threadIdx.x;
    if (i < n_vec2) keys[i] = ulonglong2{~0ULL, ~0ULL};
}

// ---------------------------------------------------------------------------
// Scatter: 4 points/thread via 3x float4 loads.
// Key = (z_bits << 32) | index; positive-float bits are order-preserving, so
// min(key) == lexicographic min(z, index) == the stable-argsort winner.
//
// Pre-test: keys[pix] is monotonically non-increasing during this kernel, so
// a (possibly stale) normal load returns a value >= the true current value.
// Skipping the atomic when my_key >= loaded is therefore always safe; a stale
// read can only cause a redundant atomic. Cuts atomic ops ~40% (E[new-min
// events per pixel] ~ H(2.95) ~ 1.7 of 2.95 arrivals).
// ---------------------------------------------------------------------------
__global__ void scatter_points_pretest(const float4* __restrict__ pts4,
                                       const float* __restrict__ Kmat,
                                       const int* __restrict__ heightp,
                                       const int* __restrict__ widthp,
                                       unsigned long long* __restrict__ keys,
                                       int n_quads) {
    int t = blockIdx.x * blockDim.x + threadIdx.x;
    if (t >= n_quads) return;

    float fx = Kmat[0], cx = Kmat[2];
    float fy = Kmat[4], cy = Kmat[5];
    int width = widthp[0], height = heightp[0];

    float4 a = pts4[3 * t + 0];
    float4 b = pts4[3 * t + 1];
    float4 c = pts4[3 * t + 2];
    unsigned int i0 = 4u * (unsigned int)t;

    float px[4] = {a.x, a.w, b.z, c.y};
    float py[4] = {a.y, b.x, b.w, c.z};
    float pz[4] = {a.z, b.y, c.x, c.w};

    int  pix[4];
    bool valid[4];
    unsigned long long key[4];

#pragma unroll
    for (int k = 0; k < 4; ++k) {
        // Match numpy bit-for-bit: IEEE f32 mul, div, add, round-half-even.
        float uf = rintf(fx * px[k] / pz[k] + cx);
        float vf = rintf(fy * py[k] / pz[k] + cy);
        valid[k] = (pz[k] > 0.0f) &&
                   (uf >= 0.0f) && (uf < (float)width) &&
                   (vf >= 0.0f) && (vf < (float)height);
        pix[k] = (int)vf * width + (int)uf;
        key[k] = ((unsigned long long)__float_as_uint(pz[k]) << 32) |
                 (i0 + (unsigned int)k);
    }

    // Independent pre-test loads (issued before any atomic).
    unsigned long long cur[4];
#pragma unroll
    for (int k = 0; k < 4; ++k) {
        cur[k] = KEY_SENTINEL;
        if (valid[k]) cur[k] = keys[pix[k]];
    }

#pragma unroll
    for (int k = 0; k < 4; ++k) {
        if (valid[k] && key[k] < cur[k]) {
            atomicMin(&keys[pix[k]], key[k]);
        }
    }
}

// ---------------------------------------------------------------------------
// Resolve: 4 pixels/thread. Vectorized key loads, 4 independent color
// gathers in flight, coalesced float4 stores (48 B/thread, 16B-aligned).
// ---------------------------------------------------------------------------
__global__ void resolve_pixels4(const unsigned long long* __restrict__ keys,
                                const float* __restrict__ colors,
                                float* __restrict__ out,
                                int n_quads) {
    int t = blockIdx.x * blockDim.x + threadIdx.x;
    if (t >= n_quads) return;

    int base = 4 * t;
    ulonglong2 k01 = *(const ulonglong2*)(keys + base);
    ulonglong2 k23 = *(const ulonglong2*)(keys + base + 2);
    unsigned long long kk[4] = {k01.x, k01.y, k23.x, k23.y};

    float c[12];
#pragma unroll
    for (int j = 0; j < 4; ++j) {
        float r = 0.0f, g = 0.0f, b = 0.0f;
        if (kk[j] != KEY_SENTINEL) {
            unsigned int idx = (unsigned int)(kk[j] & 0xFFFFFFFFu);
            r = colors[3 * idx + 0];
            g = colors[3 * idx + 1];
            b = colors[3 * idx + 2];
        }
        c[3 * j + 0] = r;
        c[3 * j + 1] = g;
        c[3 * j + 2] = b;
    }

    float4* o = (float4*)(out + 3 * (size_t)base);   // 48*t bytes: 16B aligned
    o[0] = float4{c[0], c[1], c[2],  c[3]};
    o[1] = float4{c[4], c[5], c[6],  c[7]};
    o[2] = float4{c[8], c[9], c[10], c[11]};
}

// ---------------------------------------------------------------------------
extern "C" void kernel_launch(void* const* d_in, const int* in_sizes, int n_in,
                              void* d_out, int out_size, void* d_ws, size_t ws_size,
                              hipStream_t stream) {
    const float4* pts4  = (const float4*)d_in[0];  // (N,3) as float4[3N/4]
    const float* colors = (const float*)d_in[1];   // (N,3)
    const float* Kmat   = (const float*)d_in[2];   // (3,3)
    const int*   hgt    = (const int*)d_in[3];     // scalar
    const int*   wid    = (const int*)d_in[4];     // scalar

    float* out = (float*)d_out;                    // (H,W,3) f32
    unsigned long long* keys = (unsigned long long*)d_ws;  // NPIX u64 = 10.5 MB

    int n       = in_sizes[0] / 3;                 // number of points
    int n_quads = n / 4;                           // N divisible by 4
    const int B = 256;

    int n_vec2 = NPIX / 2;
    init_keys_vec<<<(n_vec2 + B - 1) / B, B, 0, stream>>>(
        (ulonglong2*)keys, n_vec2);
    scatter_points_pretest<<<(n_quads + B - 1) / B, B, 0, stream>>>(
        pts4, Kmat, hgt, wid, keys, n_quads);
    int npix_quads = NPIX / 4;
    resolve_pixels4<<<(npix_quads + B - 1) / B, B, 0, stream>>>(
        keys, colors, out, npix_quads);
}